// Round 1
// baseline (199.773 us; speedup 1.0000x reference)
//
#include <hip/hip_runtime.h>
#include <math.h>
#include <float.h>

// x is (T,B,C,W,H) = (128,8,32,32,32) f32. Per-pixel pair of linear recurrences
// over t plus running maxes; drive normalization cancels inside the second
// (linear) scan, so one forward pass per pixel suffices.
//
// This version: 4 adjacent pixels per thread (float4 / dwordx4 loads = 1 KiB
// per wave-instruction) + explicit ping-pong register pipeline (2 batches of 8
// float4 loads in flight => 16 KiB/wave, 64 KiB/CU outstanding) to saturate HBM.
// Grid = 65536 threads = 256 blocks of 256 = exactly 1 block/CU.
#define T_STEPS 128
#define NPIX   (8 * 32 * 32 * 32)   // 262144 pixels per t-slice
#define CHW    (32 * 32 * 32)       // 32768 (param broadcast period)
#define PIXPT  4
#define NTHR   (NPIX / PIXPT)       // 65536 threads
#define S4     (NPIX / 4)           // float4 stride between consecutive t-slices
#define TB     8                    // loads per pipeline stage

typedef float f32x4 __attribute__((ext_vector_type(4)));

__global__ __launch_bounds__(256) void divnorm_kernel(
    const float* __restrict__ x,
    const float* __restrict__ tau1,
    const float* __restrict__ tau2,
    const float* __restrict__ sigma,
    const float* __restrict__ nexp,
    const int*   __restrict__ t_sel,
    float* __restrict__ out)
{
    const int tid  = blockIdx.x * blockDim.x + threadIdx.x;
    if (tid >= NTHR) return;
    const int pix0 = tid * PIXPT;           // 4 adjacent pixels, same b (CHW%4==0)
    const int chw  = pix0 & (CHW - 1);      // chw..chw+3 consecutive

    const f32x4 tv1 = *(const f32x4*)(tau1 + chw);
    const f32x4 tv2 = *(const f32x4*)(tau2 + chw);
    f32x4 a1, a2;
    #pragma unroll
    for (int j = 0; j < 4; ++j) {
        a1[j] = expf(-1.0f / tv1[j]);       // keep expf (not __expf): numerics match verified kernel
        a2[j] = expf(-1.0f / tv2[j]);
    }
    const int tc = *t_sel;                  // uniform scalar broadcast (==100)

    // y1 recurrence: A_t = a1*A_{t-1} + x_t ; Bm_t = a1*(Bm_{t-1} + A_{t-1});
    //   y1[t] = Bm before update (y1[0] = 0).
    // y2' (un-normalized): c_t = a2*c_{t-1} + y1[t]; y2'[t] = c before update.
    f32x4 A  = (f32x4)0.0f;
    f32x4 Bm = (f32x4)0.0f;
    f32x4 c2 = (f32x4)0.0f;
    f32x4 m1 = (f32x4)(-INFINITY);
    f32x4 m2 = (f32x4)(-INFINITY);
    f32x4 y1c = (f32x4)0.0f, y2c = (f32x4)0.0f;

    const f32x4* __restrict__ xp = (const f32x4*)x + tid;

    auto step = [&](const f32x4 xv, const int t) {
        const f32x4 y1 = Bm;                // y1[t]
        const f32x4 nA = a1 * A + xv;
        Bm = a1 * (Bm + A);                 // uses old A
        A  = nA;
        const f32x4 y2 = c2;                // y2'[t]
        c2 = a2 * c2 + y1;
        #pragma unroll
        for (int j = 0; j < 4; ++j) {
            m1[j] = fmaxf(m1[j], y1[j]);
            m2[j] = fmaxf(m2[j], y2[j]);
        }
        if (t == tc) { y1c = y1; y2c = y2; }   // tc is wave-uniform; cheap select
    };

    // Ping-pong pipeline: two 8-deep float4 batches. All buffer indices are
    // compile-time constants (rule #20: no runtime-indexed register arrays).
    f32x4 bA[TB], bB[TB];
    #pragma unroll
    for (int i = 0; i < TB; ++i) bA[i] = xp[i * S4];
    #pragma unroll
    for (int i = 0; i < TB; ++i) bB[i] = xp[(TB + i) * S4];

    #pragma unroll 1
    for (int tb = 0; tb < T_STEPS; tb += 2 * TB) {   // 8 iterations
        #pragma unroll
        for (int i = 0; i < TB; ++i) step(bA[i], tb + i);
        if (tb + 2 * TB < T_STEPS) {
            #pragma unroll
            for (int i = 0; i < TB; ++i) bA[i] = xp[(tb + 2 * TB + i) * S4];
        }
        #pragma unroll
        for (int i = 0; i < TB; ++i) step(bB[i], tb + TB + i);
        if (tb + 3 * TB < T_STEPS) {
            #pragma unroll
            for (int i = 0; i < TB; ++i) bB[i] = xp[(tb + 3 * TB + i) * S4];
        }
    }

    // drive[tc] = y1[tc]/max_t y1 ; norm[tc] = y2'[tc]/max_t y2'  (M1 cancels)
    const f32x4 sg = *(const f32x4*)(sigma + chw);
    const f32x4 nv = *(const f32x4*)(nexp + chw);
    f32x4 res;
    #pragma unroll
    for (int j = 0; j < 4; ++j) {
        const float drive = y1c[j] / m1[j];
        const float nrm   = y2c[j] / m2[j];
        const float id    = fabsf(powf(drive, nv[j]));
        const float nr    = fabsf(powf(nrm,  nv[j])) + sg[j];
        float r = id / nr;
        // jnp.nan_to_num defaults: nan->0, +inf->FLT_MAX, -inf->-FLT_MAX
        if (isnan(r))      r = 0.0f;
        else if (isinf(r)) r = copysignf(FLT_MAX, r);
        res[j] = r;
    }
    *(f32x4*)(out + pix0) = res;
}

extern "C" void kernel_launch(void* const* d_in, const int* in_sizes, int n_in,
                              void* d_out, int out_size, void* d_ws, size_t ws_size,
                              hipStream_t stream) {
    const float* x     = (const float*)d_in[0];
    const float* tau1  = (const float*)d_in[1];
    const float* tau2  = (const float*)d_in[2];
    const float* sigma = (const float*)d_in[3];
    const float* nexp  = (const float*)d_in[4];
    const int*   t_sel = (const int*)d_in[5];
    // d_in[6] = t_steps (==128, compile-time constant here)
    float* out = (float*)d_out;

    const int threads = 256;
    const int blocks  = NTHR / threads;   // 256 = 1 block per CU
    divnorm_kernel<<<blocks, threads, 0, stream>>>(x, tau1, tau2, sigma, nexp, t_sel, out);
}